// Round 1
// 255.472 us; speedup vs baseline: 1.0664x; 1.0664x over previous
//
#include <hip/hip_runtime.h>

#define B_   64
#define P_   12273
#define J_   80
#define MOT_ 94
#define K_   64
#define H_   128
#define Q_   340      // NB*WN
#define NE_  36819    // P*3
#define MK_  6016     // MOT*K
#define PW_  12288    // padded P for w_t rows

typedef float v4f  __attribute__((ext_vector_type(4)));
typedef float v8f  __attribute__((ext_vector_type(8)));
typedef float v16f __attribute__((ext_vector_type(16)));
#define AS4 __attribute__((address_space(4)))

__device__ __forceinline__ const AS4 float* unif(const float* p){
  return (const AS4 float*)(unsigned long long)p;
}
__device__ __forceinline__ const AS4 v4f* univ4(const float* p){
  return (const AS4 v4f*)(unsigned long long)p;
}
__device__ __forceinline__ const AS4 v8f* univ8(const float* p){
  return (const AS4 v8f*)(unsigned long long)p;
}
__device__ __forceinline__ const AS4 v16f* univ16(const float* p){
  return (const AS4 v16f*)(unsigned long long)p;
}

// ---- K1 "prep": fused fieldnet + tm transpose + skin transpose + lacc init
__global__ __launch_bounds__(256) void k_prep(
    const float* __restrict__ query, const float* __restrict__ mwl,
    const float* __restrict__ tm,    const float* __restrict__ W1,
    const float* __restrict__ b1,    const float* __restrict__ W2,
    const float* __restrict__ b2,    const float* __restrict__ cps,
    const float* __restrict__ cpm,   const float* __restrict__ cts,
    const float* __restrict__ ctm,   const float* __restrict__ skin,
    float* __restrict__ G,           float* __restrict__ tm_t,
    float* __restrict__ w_t,         float* __restrict__ lacc)
{
  __shared__ float smem[80 * 65];
  int blk = blockIdx.x;
  int t = threadIdx.x;
  if (blk < 1280){
    int lane = t & 63;
    int wid = __builtin_amdgcn_readfirstlane(t >> 6);
    int bj = blk * 4 + wid;
    int b = bj / J_, l = bj - b * J_;
    float* hs = smem + wid * 80;
    float acc = 0.f;
    const AS4 float* mp = unif(mwl + l * MOT_);
    const float* tp = tm + (size_t)b * MK_ + lane;
    #pragma unroll 2
    for (int j = 0; j < MOT_; j++){
      float w = mp[j]; w = w > 0.f ? w : 0.f;
      acc = fmaf(w, tp[j * K_], acc);
    }
    hs[3 + lane] = acc;
    if (lane < 3) hs[lane] = query[(size_t)bj * 3 + lane];
    __syncthreads();
    float a1 = b1[lane], a2 = b1[lane + 64];
    for (int i = 0; i < 3 + K_; i++){
      float hv = hs[i];
      a1 = fmaf(hv, W1[i * H_ + lane], a1);
      a2 = fmaf(hv, W1[i * H_ + 64 + lane], a2);
    }
    a1 = a1 > 0.f ? a1 : 0.f;
    a2 = a2 > 0.f ? a2 : 0.f;
    const AS4 float* b2c = unif(b2);
    float rt[6];
    #pragma unroll
    for (int o = 0; o < 6; o++){
      float po = fmaf(a1, W2[lane * 6 + o], a2 * W2[(lane + 64) * 6 + o]);
      #pragma unroll
      for (int off = 32; off; off >>= 1) po += __shfl_xor(po, off);
      rt[o] = po + b2c[o];
    }
    const float D2R = 0.017453292519943295f;
    float ax = fmaf(rt[0], cps[0], cpm[0]) * D2R;
    float ay = fmaf(rt[1], cps[1], cpm[1]) * D2R;
    float az = fmaf(rt[2], cps[2], cpm[2]) * D2R;
    float tx = fmaf(hs[0] + rt[3], cts[0], ctm[0]);
    float ty = fmaf(hs[1] + rt[4], cts[1], ctm[1]);
    float tz = fmaf(hs[2] + rt[5], cts[2], ctm[2]);
    float sx, cx, sy, cy, sz, cz;
    sincosf(ax, &sx, &cx); sincosf(ay, &sy, &cy); sincosf(az, &sz, &cz);
    if (lane == 0){
      float4 r0 = make_float4(cz*cy, cz*sy*sx - sz*cx, cz*sy*cx + sz*sx, tx);
      float4 r1 = make_float4(sz*cy, sz*sy*sx + cz*cx, sz*sy*cx - cz*sx, ty);
      float4 r2 = make_float4(-sy,   cy*sx,            cy*cx,            tz);
      float4* g = (float4*)(G + (size_t)bj * 12);
      g[0] = r0; g[1] = r1; g[2] = r2;
    }
  } else if (blk < 1374){
    int m0 = (blk - 1280) * 64;
    int ml = t & 63, g = t >> 6;
    #pragma unroll
    for (int r = 0; r < 16; r++){
      int b = g * 16 + r;
      smem[ml * 65 + b] = tm[(size_t)b * MK_ + m0 + ml];
    }
    __syncthreads();
    int bl = t & 63;
    #pragma unroll
    for (int r = 0; r < 16; r++){
      int m = g * 16 + r;
      tm_t[(size_t)(m0 + m) * 64 + bl] = smem[m * 65 + bl];
    }
  } else if (blk < 1566){
    int p0 = (blk - 1374) * 64;
    #pragma unroll
    for (int k = 0; k < 20; k++){
      int idx = k * 256 + t;
      int pl = idx / 80, j = idx - pl * 80;
      int p = p0 + pl;
      smem[j * 65 + pl] = (p < P_) ? skin[(size_t)p * J_ + j] : 0.f;
    }
    __syncthreads();
    #pragma unroll
    for (int k = 0; k < 20; k++){
      int idx = k * 256 + t;
      int j = idx >> 6, pl = idx & 63;
      w_t[(size_t)j * PW_ + p0 + pl] = smem[j * 65 + pl];
    }
  } else {
    if (t < 2) lacc[t] = 0.f;
  }
}

// ---- K2: detailkey partial GEMM. grid (6, 94). No LDS, no atomics.
//      4 waves share m-range [by*64, +64); wave wid owns b-slice [wid*16, +16).
//      Wd prefetched 4-deep (VMEM), tm_t rows 2-deep (SMEM s_load_dwordx16).
__global__ __launch_bounds__(256) void k_dkey(
    const float* __restrict__ tm_t, const float* __restrict__ Wd,
    float* __restrict__ part)
{
  int t = threadIdx.x;
  int lane = t & 63;
  int wid = __builtin_amdgcn_readfirstlane(t >> 6);
  int qt = blockIdx.x;
  int q = qt * 64 + lane;
  bool vq = q < Q_;
  int m0 = blockIdx.y * 64;
  const AS4 v16f* tr = univ16(tm_t);
  float acc[16];
  #pragma unroll
  for (int i = 0; i < 16; i++) acc[i] = 0.f;
  float wbuf[4];
  #pragma unroll
  for (int i = 0; i < 4; i++)
    wbuf[i] = vq ? Wd[(size_t)(m0 + i) * Q_ + q] : 0.f;
  v16f tb0 = tr[(size_t)(m0 + 0) * 4 + wid];
  v16f tb1 = tr[(size_t)(m0 + 1) * 4 + wid];
  #pragma unroll 4
  for (int mm = 0; mm < 60; mm++){
    float wd = wbuf[mm & 3];
    wbuf[mm & 3] = vq ? Wd[(size_t)(m0 + mm + 4) * Q_ + q] : 0.f;
    v16f tv = tb0; tb0 = tb1;
    tb1 = tr[(size_t)(m0 + mm + 2) * 4 + wid];
    #pragma unroll
    for (int i = 0; i < 16; i++) acc[i] = fmaf(tv[i], wd, acc[i]);
  }
  #pragma unroll
  for (int mm = 60; mm < 64; mm++){
    float wd = wbuf[mm & 3];
    v16f tv = tb0; tb0 = tb1;
    if (mm < 62) tb1 = tr[(size_t)(m0 + mm + 2) * 4 + wid];
    #pragma unroll
    for (int i = 0; i < 16; i++) acc[i] = fmaf(tv[i], wd, acc[i]);
  }
  float* pb = part + ((size_t)blockIdx.y * 6 + qt) * 4096 + (size_t)(wid * 16) * 64;
  #pragma unroll
  for (int i = 0; i < 16; i++) pb[i * 64 + lane] = acc[i];
}

// ---- K3: reduce partials + bd -> dk_t[q*64+b]. 680 blocks, 8-way d-split per j.
__global__ __launch_bounds__(256) void k_dkred(
    const float* __restrict__ part, const float* __restrict__ bd,
    float* __restrict__ dk_t, int S)
{
  int t = threadIdx.x;
  int jj = blockIdx.x * 32 + (t >> 3);   // 680*32 = 21760 = B_*Q_ exactly
  int dl = t & 7;
  int b = jj / Q_, q = jj - b * Q_;
  int qt = q >> 6, ql = q & 63;
  const float* pp = part + (size_t)qt * 4096 + b * 64 + ql;
  float s = 0.f;
  for (int d = dl; d < S; d += 8) s += pp[(size_t)d * 6 * 4096];
  s += __shfl_xor(s, 1); s += __shfl_xor(s, 2); s += __shfl_xor(s, 4);
  if (dl == 0) dk_t[q * 64 + b] = bd[q] + s;
}

// ---- K4 v3: detail einsum. 4 waves/block, each wave owns 16 b -> 16 FMA per
//      DPSD load (dk rows arrive as 64B s_load into SGPRs). DPSD prefetched
//      2 groups (10 dwords) deep per thread. 256 thr -> ~48 VGPR -> high
//      occupancy; loads unconditional via clamped e. Accumulation order per
//      (b,e) identical to previous version (bitwise-stable numerics).
__device__ __forceinline__ void dconsume(const AS4 v16f* dkv, int qa, int wid,
                                         const float* dc, float* acc,
                                         float& sq, bool doSq)
{
  v16f r0 = dkv[(qa + 0) * 4 + wid];
  v16f r1 = dkv[(qa + 1) * 4 + wid];
  v16f r2 = dkv[(qa + 2) * 4 + wid];
  v16f r3 = dkv[(qa + 3) * 4 + wid];
  v16f r4 = dkv[(qa + 4) * 4 + wid];
  if (doSq){
    #pragma unroll
    for (int i = 0; i < 5; i++) sq = fmaf(dc[i], dc[i], sq);
  }
  #pragma unroll
  for (int i = 0; i < 16; i++){
    acc[i] = fmaf(r0[i], dc[0], acc[i]);
    acc[i] = fmaf(r1[i], dc[1], acc[i]);
    acc[i] = fmaf(r2[i], dc[2], acc[i]);
    acc[i] = fmaf(r3[i], dc[3], acc[i]);
    acc[i] = fmaf(r4[i], dc[4], acc[i]);
  }
}

__global__ __launch_bounds__(256) void k_detail(
    const float* __restrict__ DPSD, const float* __restrict__ dk_t,
    float* __restrict__ stg0, float* __restrict__ out,
    float* __restrict__ lacc, int qn)
{
  int t = threadIdx.x;
  int lane = t & 63;
  int wid = __builtin_amdgcn_readfirstlane(t >> 6);  // 0..3
  int b0 = wid * 16;
  int e = blockIdx.x * 64 + lane;
  bool ve = e < NE_;
  int q0 = blockIdx.y * qn;
  const AS4 v16f* dkv = univ16(dk_t);
  const float* Dp = DPSD + (ve ? e : 0);
  float acc[16];
  #pragma unroll
  for (int i = 0; i < 16; i++) acc[i] = 0.f;
  float sq = 0.f;
  bool doSq = (wid == 0);
  float da[5], db[5];
  #pragma unroll
  for (int i = 0; i < 5; i++) da[i] = Dp[(size_t)(q0 + i) * NE_];
  #pragma unroll
  for (int i = 0; i < 5; i++) db[i] = Dp[(size_t)(q0 + 5 + i) * NE_];
  int ng = qn / 5;                  // 34 (nqh=2) or 68 (nqh=1): always even
  int g = 0;
  for (; g + 2 < ng; g += 2){
    int qa = q0 + g * 5;
    float ta[5], tb[5];
    #pragma unroll
    for (int i = 0; i < 5; i++) ta[i] = Dp[(size_t)(qa + 10 + i) * NE_];
    dconsume(dkv, qa, wid, da, acc, sq, doSq);
    #pragma unroll
    for (int i = 0; i < 5; i++) da[i] = ta[i];
    #pragma unroll
    for (int i = 0; i < 5; i++) tb[i] = Dp[(size_t)(qa + 15 + i) * NE_];
    dconsume(dkv, qa + 5, wid, db, acc, sq, doSq);
    #pragma unroll
    for (int i = 0; i < 5; i++) db[i] = tb[i];
  }
  // tail: g == ng-2, da = group ng-2, db = group ng-1
  dconsume(dkv, q0 + (ng - 2) * 5, wid, da, acc, sq, doSq);
  dconsume(dkv, q0 + (ng - 1) * 5, wid, db, acc, sq, doSq);
  if (ve){
    bool toOut = (blockIdx.y + 1 == gridDim.y);
    float* dst = toOut ? (out + 1 + e) : (stg0 + e);
    #pragma unroll
    for (int i = 0; i < 16; i++)
      dst[(size_t)(b0 + i) * NE_] = acc[i];
  }
  if (doSq){
    if (!ve) sq = 0.f;
    #pragma unroll
    for (int off = 32; off; off >>= 1) sq += __shfl_xor(sq, off);
    if (lane == 0) atomicAdd(&lacc[1], sq);
  }
}

// ---- K5: LBS skinning; G rows via s_load; combines detail halves + scale.
__global__ __launch_bounds__(256) void k_skin(
    const float* __restrict__ G, const float* __restrict__ w_t,
    const float* __restrict__ rest, const float* __restrict__ in_pc,
    const float* __restrict__ stg0, const float* __restrict__ rstd,
    const float* __restrict__ rmean,
    float* __restrict__ out, float* __restrict__ lacc, int two)
{
  int t = threadIdx.x;
  int lane = t & 63;
  int wid = __builtin_amdgcn_readfirstlane(t >> 6);  // 0..3
  int p  = blockIdx.x * 64 + lane;
  int bA = blockIdx.y * 8 + wid * 2;
  const AS4 v4f* gA = univ4(G + (size_t)bA * J_ * 12);
  const AS4 v4f* gB = univ4(G + ((size_t)bA + 1) * J_ * 12);
  float accA[12], accB[12];
  #pragma unroll
  for (int c = 0; c < 12; c++){ accA[c] = 0.f; accB[c] = 0.f; }
  const float* wp = w_t + p;
  #pragma unroll 4
  for (int j = 0; j < J_; j++){
    float w = wp[(size_t)j * PW_];
    v4f a0 = gA[j * 3 + 0], a1 = gA[j * 3 + 1], a2 = gA[j * 3 + 2];
    v4f c0 = gB[j * 3 + 0], c1 = gB[j * 3 + 1], c2 = gB[j * 3 + 2];
    #pragma unroll
    for (int c = 0; c < 4; c++){
      accA[c]     = fmaf(w, a0[c], accA[c]);
      accA[4 + c] = fmaf(w, a1[c], accA[4 + c]);
      accA[8 + c] = fmaf(w, a2[c], accA[8 + c]);
      accB[c]     = fmaf(w, c0[c], accB[c]);
      accB[4 + c] = fmaf(w, c1[c], accB[4 + c]);
      accB[8 + c] = fmaf(w, c2[c], accB[8 + c]);
    }
  }
  bool vp = p < P_;
  float vx = 0.f, vy = 0.f, vz = 0.f;
  if (vp){ vx = rest[p * 3]; vy = rest[p * 3 + 1]; vz = rest[p * 3 + 2]; }
  float srs[3], srm[3];
  #pragma unroll
  for (int x = 0; x < 3; x++){ srs[x] = rstd[x]; srm[x] = rmean[x]; }
  float lsum = 0.f;
  if (vp){
    size_t baseA = ((size_t)bA * P_ + p) * 3;
    size_t baseB = baseA + (size_t)P_ * 3;
    #pragma unroll
    for (int x = 0; x < 3; x++){
      float det = out[1 + baseA + x];
      if (two) det += stg0[baseA + x];
      float v = fmaf(accA[x*4+0], vx, fmaf(accA[x*4+1], vy, fmaf(accA[x*4+2], vz, accA[x*4+3])));
      v += fmaf(det, srs[x], srm[x]);
      lsum += fabsf(in_pc[baseA + x] - v);
      out[1 + baseA + x] = v;
    }
    #pragma unroll
    for (int x = 0; x < 3; x++){
      float det = out[1 + baseB + x];
      if (two) det += stg0[baseB + x];
      float v = fmaf(accB[x*4+0], vx, fmaf(accB[x*4+1], vy, fmaf(accB[x*4+2], vz, accB[x*4+3])));
      v += fmaf(det, srs[x], srm[x]);
      lsum += fabsf(in_pc[baseB + x] - v);
      out[1 + baseB + x] = v;
    }
  }
  #pragma unroll
  for (int off = 32; off; off >>= 1) lsum += __shfl_xor(lsum, off);
  __shared__ float red[4];
  if (lane == 0) red[wid] = lsum;
  __syncthreads();
  if (t == 0) atomicAdd(&lacc[0], red[0] + red[1] + red[2] + red[3]);
}

// ---- K6: finalize scalar loss
__global__ void k_finalize(const float* __restrict__ lacc, float* __restrict__ out){
  if (threadIdx.x == 0 && blockIdx.x == 0){
    float loss = lacc[0] * (1.f / 2356416.f) + 1e-4f * (lacc[1] * (1.f / 12518460.f));
    out[0] = loss;
  }
}

extern "C" void kernel_launch(void* const* d_in, const int* in_sizes, int n_in,
                              void* d_out, int out_size, void* d_ws, size_t ws_size,
                              hipStream_t stream){
  const float* in_pc = (const float*)d_in[0];
  const float* rest  = (const float*)d_in[2];
  const float* skin  = (const float*)d_in[3];
  const float* mwl   = (const float*)d_in[4];
  const float* query = (const float*)d_in[5];
  const float* cps   = (const float*)d_in[6];
  const float* cpm   = (const float*)d_in[7];
  const float* cts   = (const float*)d_in[8];
  const float* ctm   = (const float*)d_in[9];
  const float* W1    = (const float*)d_in[10];
  const float* b1    = (const float*)d_in[11];
  const float* W2    = (const float*)d_in[12];
  const float* b2    = (const float*)d_in[13];
  const float* tm    = (const float*)d_in[14];
  const float* Wd    = (const float*)d_in[15];
  const float* bd    = (const float*)d_in[16];
  const float* DPSD  = (const float*)d_in[17];
  const float* rstd  = (const float*)d_in[18];
  const float* rmean = (const float*)d_in[19];
  float* out = (float*)d_out;

  float* ws   = (float*)d_ws;
  float* G    = ws;                 // 61440
  float* dk_t = G + 61440;          // 21760
  float* lacc = dk_t + 21760;       // 64 (pad)
  float* tm_t = lacc + 64;          // 385024
  float* w_t  = tm_t + 385024;      // 983040
  float* un   = w_t + 983040;       // union: part (94*24576=2310144) then stg0 (2356416)
  // part is dead before k_detail writes stg0 -> alias them.

  size_t have = ws_size / 4;
  int nqh = (have >= (size_t)(1451328 + 2356416)) ? 2 : 1;
  int qn = Q_ / nqh;

  k_prep    <<<1567, 256, 0, stream>>>(query, mwl, tm, W1, b1, W2, b2,
                                       cps, cpm, cts, ctm, skin,
                                       G, tm_t, w_t, lacc);
  k_dkey    <<<dim3(6, 94), 256, 0, stream>>>(tm_t, Wd, un);
  k_dkred   <<<680, 256, 0, stream>>>(un, bd, dk_t, 94);
  k_detail  <<<dim3(576, nqh), 256, 0, stream>>>(DPSD, dk_t, un, out, lacc, qn);
  k_skin    <<<dim3(192, 8), 256, 0, stream>>>(G, w_t, rest, in_pc, un, rstd, rmean,
                                               out, lacc, nqh - 1);
  k_finalize<<<1, 64, 0, stream>>>(lacc, out);
}